// Round 7
// baseline (8433.285 us; speedup 1.0000x reference)
//
#include <hip/hip_runtime.h>
#include <hip/hip_bf16.h>

#define FDIM 1024
#define NH   16
#define HD   64
#define SEQ  2048
#define QT   8          // q rows per attention block

// Complex GEMM over ONE batch: Y = X @ W + b, X=[2048,1024], W=[1024,1024],
// all fp32. mode 0: write head-split [H,S,D]; mode 1: write flat [S,F].
__global__ __launch_bounds__(256)
void cgemm_kernel(const float* __restrict__ xr, const float* __restrict__ xi,
                  const float* __restrict__ wr, const float* __restrict__ wi,
                  const float* __restrict__ br, const float* __restrict__ bi,
                  float* __restrict__ outR, float* __restrict__ outI, int mode)
{
    __shared__ float Xr[16][68], Xi[16][68];   // [kk][m] transposed
    __shared__ float Wr[16][68], Wi[16][68];   // [kk][n]

    const int tid = threadIdx.x;
    const int n0  = blockIdx.x * 64;
    const int m0  = blockIdx.y * 64;

    float yr[4][4] = {}, yi[4][4] = {};

    const int lxr = tid >> 2;          // 0..63 : m-row within tile
    const int lxk = (tid & 3) * 4;     // k offset 0..12
    const int lwk = tid >> 4;          // 0..15  : k-row
    const int lwn = (tid & 15) * 4;    // n offset 0..60
    const int r0  = (tid >> 4) * 4;    // compute row group
    const int c0  = (tid & 15) * 4;    // compute col group

    for (int k0 = 0; k0 < FDIM; k0 += 16) {
        {   // stage X (transposed)
            float4 t;
            t = *reinterpret_cast<const float4*>(xr + (long)(m0 + lxr) * FDIM + k0 + lxk);
            Xr[lxk + 0][lxr] = t.x; Xr[lxk + 1][lxr] = t.y;
            Xr[lxk + 2][lxr] = t.z; Xr[lxk + 3][lxr] = t.w;
            t = *reinterpret_cast<const float4*>(xi + (long)(m0 + lxr) * FDIM + k0 + lxk);
            Xi[lxk + 0][lxr] = t.x; Xi[lxk + 1][lxr] = t.y;
            Xi[lxk + 2][lxr] = t.z; Xi[lxk + 3][lxr] = t.w;
        }
        {   // stage W
            float4 t;
            t = *reinterpret_cast<const float4*>(wr + (long)(k0 + lwk) * FDIM + n0 + lwn);
            *reinterpret_cast<float4*>(&Wr[lwk][lwn]) = t;
            t = *reinterpret_cast<const float4*>(wi + (long)(k0 + lwk) * FDIM + n0 + lwn);
            *reinterpret_cast<float4*>(&Wi[lwk][lwn]) = t;
        }
        __syncthreads();

        #pragma unroll
        for (int kk = 0; kk < 16; kk++) {
            float ar[4], ai[4], brv[4], biv[4];
            *(float4*)ar  = *(const float4*)&Xr[kk][r0];
            *(float4*)ai  = *(const float4*)&Xi[kk][r0];
            *(float4*)brv = *(const float4*)&Wr[kk][c0];
            *(float4*)biv = *(const float4*)&Wi[kk][c0];
            #pragma unroll
            for (int i = 0; i < 4; i++)
                #pragma unroll
                for (int j = 0; j < 4; j++) {
                    yr[i][j] += ar[i] * brv[j] - ai[i] * biv[j];
                    yi[i][j] += ar[i] * biv[j] + ai[i] * brv[j];
                }
        }
        __syncthreads();
    }

    const float4 bre = *reinterpret_cast<const float4*>(br + n0 + c0);
    const float4 bim = *reinterpret_cast<const float4*>(bi + n0 + c0);

    #pragma unroll
    for (int i = 0; i < 4; i++) {
        const int m = m0 + r0 + i;           // 0..2047 == s
        long addr;
        if (mode == 0) {
            const int h = n0 >> 6;           // tile width == HD
            addr = ((long)h * SEQ + m) * HD + c0;
        } else {
            addr = (long)m * FDIM + n0 + c0;
        }
        float4 vr, vi;
        vr.x = yr[i][0] + bre.x; vr.y = yr[i][1] + bre.y;
        vr.z = yr[i][2] + bre.z; vr.w = yr[i][3] + bre.w;
        vi.x = yi[i][0] + bim.x; vi.y = yi[i][1] + bim.y;
        vi.z = yi[i][2] + bim.z; vi.w = yi[i][3] + bim.w;
        *reinterpret_cast<float4*>(outR + addr) = vr;
        *reinterpret_cast<float4*>(outI + addr) = vi;
    }
}

// Two-pass (exact) softmax attention over ONE batch. One block = (h, 8 q-rows).
// QKV fp32 per-b [H,S,D]; mask fp32 pre-offset to this batch; A out per-b [S,F].
__global__ __launch_bounds__(256)
void attn2_kernel(const float* __restrict__ Qr, const float* __restrict__ Qi,
                  const float* __restrict__ Kr, const float* __restrict__ Ki,
                  const float* __restrict__ Vr, const float* __restrict__ Vi,
                  const float* __restrict__ mask,
                  float* __restrict__ Ar, float* __restrict__ Ai)
{
    __shared__ float S[QT][SEQ];                 // 64 KB
    __shared__ float Krs[64][68], Kis[64][68];   // K tile (reused as V tile)
    __shared__ float Qrs[QT][68], Qis[QT][68];
    __shared__ float red[QT][33];
    __shared__ float mrow[QT], linv[QT];

    const int tid = threadIdx.x;
    const int q0  = blockIdx.x * QT;
    const int h   = blockIdx.y;
    const long head_base = (long)h * SEQ * HD;

    // ---- stage Q (float4) ----
    for (int idx = tid; idx < QT * HD / 4; idx += 256) {
        const int r = idx >> 4, d = (idx & 15) * 4;
        *reinterpret_cast<float4*>(&Qrs[r][d]) =
            *reinterpret_cast<const float4*>(Qr + head_base + (long)(q0 + r) * HD + d);
        *reinterpret_cast<float4*>(&Qis[r][d]) =
            *reinterpret_cast<const float4*>(Qi + head_base + (long)(q0 + r) * HD + d);
    }

    const int r   = tid >> 5;        // 0..7   owned q-row
    const int lk  = tid & 31;        // 0..31
    const float scale = 0.125f;      // 1/sqrt(64)

    // ---- phase 1: scores S[r][k] = (Qr.Kr + Qi.Ki)*scale + maskadd ----
    for (int kt = 0; kt < SEQ; kt += 64) {
        __syncthreads();             // protect K-tile reuse (and Q staging, iter 0)
        for (int idx = tid; idx < 64 * HD / 4; idx += 256) {
            const int kk = idx >> 4, d = (idx & 15) * 4;
            *reinterpret_cast<float4*>(&Krs[kk][d]) =
                *reinterpret_cast<const float4*>(Kr + head_base + (long)(kt + kk) * HD + d);
            *reinterpret_cast<float4*>(&Kis[kk][d]) =
                *reinterpret_cast<const float4*>(Ki + head_base + (long)(kt + kk) * HD + d);
        }
        __syncthreads();

        const int kkA = lk, kkB = lk + 32;
        float accA = 0.0f, accB = 0.0f;
        #pragma unroll
        for (int d = 0; d < 64; d += 4) {
            const float4 qr = *(const float4*)&Qrs[r][d];
            const float4 qi = *(const float4*)&Qis[r][d];
            const float4 ra = *(const float4*)&Krs[kkA][d];
            const float4 ia = *(const float4*)&Kis[kkA][d];
            const float4 rb = *(const float4*)&Krs[kkB][d];
            const float4 ib = *(const float4*)&Kis[kkB][d];
            accA += qr.x*ra.x + qr.y*ra.y + qr.z*ra.z + qr.w*ra.w
                  + qi.x*ia.x + qi.y*ia.y + qi.z*ia.z + qi.w*ia.w;
            accB += qr.x*rb.x + qr.y*rb.y + qr.z*rb.z + qr.w*rb.w
                  + qi.x*ib.x + qi.y*ib.y + qi.z*ib.z + qi.w*ib.w;
        }
        const float mA = (1.0f - mask[kt + kkA]) * -1.0e9f;
        const float mB = (1.0f - mask[kt + kkB]) * -1.0e9f;
        S[r][kt + kkA] = accA * scale + mA;
        S[r][kt + kkB] = accB * scale + mB;
    }
    __syncthreads();

    // ---- phase 2: exact two-pass softmax (32 threads per row) ----
    {
        float mx = -3.0e38f;
        for (int k = lk; k < SEQ; k += 32) mx = fmaxf(mx, S[r][k]);
        red[r][lk] = mx;
        __syncthreads();
        if (lk == 0) {
            float m = red[r][0];
            #pragma unroll
            for (int j = 1; j < 32; j++) m = fmaxf(m, red[r][j]);
            mrow[r] = m;
        }
        __syncthreads();
        const float m = mrow[r];
        float sum = 0.0f;
        for (int k = lk; k < SEQ; k += 32) {
            const float p = __expf(S[r][k] - m);
            S[r][k] = p;
            sum += p;
        }
        red[r][lk] = sum;
        __syncthreads();
        if (lk == 0) {
            float s = 0.0f;
            #pragma unroll
            for (int j = 0; j < 32; j++) s += red[r][j];
            linv[r] = 1.0f / s;
        }
    }
    __syncthreads();

    // ---- phase 3: O[r][d] = sum_k P[r][k] * V[k][d] ----
    const int d4 = lk * 4;           // 0..124 spans [re 0..63 | im 64..127]
    const int dd = d4 & 63;
    float acc[4] = {0.f, 0.f, 0.f, 0.f};

    for (int kt = 0; kt < SEQ; kt += 64) {
        __syncthreads();             // protect V-tile reuse
        for (int idx = tid; idx < 64 * HD / 4; idx += 256) {
            const int kk = idx >> 4, d = (idx & 15) * 4;
            *reinterpret_cast<float4*>(&Krs[kk][d]) =
                *reinterpret_cast<const float4*>(Vr + head_base + (long)(kt + kk) * HD + d);
            *reinterpret_cast<float4*>(&Kis[kk][d]) =
                *reinterpret_cast<const float4*>(Vi + head_base + (long)(kt + kk) * HD + d);
        }
        __syncthreads();

        const float (*Vs)[68] = (d4 < 64) ? Krs : Kis;
        #pragma unroll 8
        for (int kk = 0; kk < 64; kk++) {
            const float p = S[r][kt + kk];
            const float4 v = *(const float4*)&Vs[kk][dd];
            acc[0] += p * v.x; acc[1] += p * v.y; acc[2] += p * v.z; acc[3] += p * v.w;
        }
    }

    const float il = linv[r];
    float* dst = ((d4 < 64) ? Ar : Ai) + (long)(q0 + r) * FDIM + h * HD + dd;
    float4 w;
    w.x = acc[0] * il; w.y = acc[1] * il; w.z = acc[2] * il; w.w = acc[3] * il;
    *reinterpret_cast<float4*>(dst) = w;
}

extern "C" void kernel_launch(void* const* d_in, const int* in_sizes, int n_in,
                              void* d_out, int out_size, void* d_ws, size_t ws_size,
                              hipStream_t stream)
{
    // Inputs fp32 (reference is float32 end-to-end); output fp32.
    const float* x_r  = (const float*)d_in[0];
    const float* x_i  = (const float*)d_in[1];
    const float* mask = (const float*)d_in[2];
    const float *Wq_r = (const float*)d_in[3],  *Wq_i = (const float*)d_in[4];
    const float *bq_r = (const float*)d_in[5],  *bq_i = (const float*)d_in[6];
    const float *Wk_r = (const float*)d_in[7],  *Wk_i = (const float*)d_in[8];
    const float *bk_r = (const float*)d_in[9],  *bk_i = (const float*)d_in[10];
    const float *Wv_r = (const float*)d_in[11], *Wv_i = (const float*)d_in[12];
    const float *bv_r = (const float*)d_in[13], *bv_i = (const float*)d_in[14];
    const float *Wo_r = (const float*)d_in[15], *Wo_i = (const float*)d_in[16];
    const float *bo_r = (const float*)d_in[17], *bo_i = (const float*)d_in[18];

    // Per-batch fp32 workspace: 8 buffers x (S*F = 2,097,152) floats = 64 MiB.
    float* ws = (float*)d_ws;
    const long NB = (long)SEQ * FDIM;          // 2,097,152 elements per buffer
    float *Qr = ws + 0 * NB, *Qi = ws + 1 * NB;
    float *Kr = ws + 2 * NB, *Ki = ws + 3 * NB;
    float *Vr = ws + 4 * NB, *Vi = ws + 5 * NB;
    float *Ar = ws + 6 * NB, *Ai = ws + 7 * NB;

    const long HALF = (long)2 * SEQ * FDIM;    // B*S*F = 4,194,304 (out_r section)

    dim3 gg(16, 32);                           // n-tiles x m-tiles (2048 rows)
    for (int b = 0; b < 2; b++) {
        const float* xb_r = x_r + (long)b * NB;
        const float* xb_i = x_i + (long)b * NB;
        float* outR = (float*)d_out + (long)b * NB;
        float* outI = (float*)d_out + HALF + (long)b * NB;

        cgemm_kernel<<<gg, 256, 0, stream>>>(xb_r, xb_i, Wq_r, Wq_i, bq_r, bq_i, Qr, Qi, 0);
        cgemm_kernel<<<gg, 256, 0, stream>>>(xb_r, xb_i, Wk_r, Wk_i, bk_r, bk_i, Kr, Ki, 0);
        cgemm_kernel<<<gg, 256, 0, stream>>>(xb_r, xb_i, Wv_r, Wv_i, bv_r, bv_i, Vr, Vi, 0);
        attn2_kernel<<<dim3(SEQ / QT, NH), 256, 0, stream>>>(Qr, Qi, Kr, Ki, Vr, Vi,
                                                             mask + (long)b * SEQ, Ar, Ai);
        cgemm_kernel<<<gg, 256, 0, stream>>>(Ar, Ai, Wo_r, Wo_i, bo_r, bo_i, outR, outI, 1);
    }
}

// Round 8
// 2637.768 us; speedup vs baseline: 3.1971x; 3.1971x over previous
//
#include <hip/hip_runtime.h>
#include <hip/hip_bf16.h>

typedef unsigned short u16;
typedef unsigned int   u32;
typedef __attribute__((ext_vector_type(8))) short bf16x8;
typedef __attribute__((ext_vector_type(4))) float f32x4;

#define FDIM 1024
#define NH   16
#define HD   64
#define SEQ  2048

#define MFMA16 __builtin_amdgcn_mfma_f32_16x16x32_bf16

__device__ __forceinline__ u16 f2bf(float f) {
    __hip_bfloat16 h = __float2bfloat16(f);
    return *reinterpret_cast<u16*>(&h);
}

struct GemmJob {
    const float *wr, *wi, *br, *bi;
    float *outR, *outI;
};

// MFMA complex GEMM: Y = X @ W + b. X [2048][1024] fp32 (one batch),
// W [1024][1024] fp32, converted to bf16 during LDS staging (W transposed).
// Tile 128x128, BK=32, 4 waves each owning a 64x64 quadrant (4x4 MFMA tiles).
// mode 0: head-split out [NH][SEQ][HD]; mode 1: flat [2048][1024].
// blockIdx.z selects job (fused Q/K/V projections).
__global__ __launch_bounds__(256)
void cgemm_mfma(const float* __restrict__ xr, const float* __restrict__ xi,
                GemmJob j0, GemmJob j1, GemmJob j2, int mode)
{
    // +8 u16 pad per 32-elem row: 80 B stride (16B-aligned, ~2-way banks)
    __shared__ u16 Xr[128][40], Xi[128][40];
    __shared__ u16 Wtr[128][40], Wti[128][40];    // transposed: [n][k]

    GemmJob job = (blockIdx.z == 0) ? j0 : (blockIdx.z == 1 ? j1 : j2);

    const int tid = threadIdx.x;
    const int n0  = blockIdx.x * 128;
    const int m0  = blockIdx.y * 128;

    const int lane = tid & 63;
    const int wv   = tid >> 6;          // wave 0..3
    const int mwo  = (wv >> 1) * 64;    // wave m-offset
    const int nwo  = (wv & 1) * 64;     // wave n-offset
    const int ml   = lane & 15;
    const int kg   = lane >> 4;         // 0..3

    // staging assignments
    const int sxm = tid >> 1;           // X row 0..127
    const int sxk = (tid & 1) * 16;     // X k-offset {0,16}
    const int swk = (tid >> 4) * 2;     // W k-pair base 0..30
    const int swn = tid & 15;           // W n base (strided by 16)

    f32x4 accr[4][4], acci[4][4];
    #pragma unroll
    for (int i = 0; i < 4; i++)
        #pragma unroll
        for (int j = 0; j < 4; j++) {
            accr[i][j] = (f32x4)(0.0f);
            acci[i][j] = (f32x4)(0.0f);
        }

    for (int k0 = 0; k0 < FDIM; k0 += 32) {
        // ---- stage X -> bf16 LDS ----
        {
            const float* s = xr + (long)(m0 + sxm) * FDIM + k0 + sxk;
            u16 t[16];
            #pragma unroll
            for (int q = 0; q < 4; q++) {
                float4 v = *(const float4*)(s + q * 4);
                t[q*4+0] = f2bf(v.x); t[q*4+1] = f2bf(v.y);
                t[q*4+2] = f2bf(v.z); t[q*4+3] = f2bf(v.w);
            }
            *(uint4*)&Xr[sxm][sxk]     = *(uint4*)&t[0];
            *(uint4*)&Xr[sxm][sxk + 8] = *(uint4*)&t[8];
            s = xi + (long)(m0 + sxm) * FDIM + k0 + sxk;
            #pragma unroll
            for (int q = 0; q < 4; q++) {
                float4 v = *(const float4*)(s + q * 4);
                t[q*4+0] = f2bf(v.x); t[q*4+1] = f2bf(v.y);
                t[q*4+2] = f2bf(v.z); t[q*4+3] = f2bf(v.w);
            }
            *(uint4*)&Xi[sxm][sxk]     = *(uint4*)&t[0];
            *(uint4*)&Xi[sxm][sxk + 8] = *(uint4*)&t[8];
        }
        // ---- stage W^T -> bf16 LDS (k-pairs packed as u32) ----
        {
            const long rowA = (long)(k0 + swk) * FDIM + n0;
            const long rowB = rowA + FDIM;
            #pragma unroll
            for (int jj = 0; jj < 8; jj++) {
                const int n = swn + 16 * jj;
                float a = job.wr[rowA + n];
                float b = job.wr[rowB + n];
                *(u32*)&Wtr[n][swk] = (u32)f2bf(a) | ((u32)f2bf(b) << 16);
                a = job.wi[rowA + n];
                b = job.wi[rowB + n];
                *(u32*)&Wti[n][swk] = (u32)f2bf(a) | ((u32)f2bf(b) << 16);
            }
        }
        __syncthreads();

        // ---- fragments ----
        bf16x8 ar[4], ai[4], nai[4], br[4], bi[4];
        #pragma unroll
        for (int i = 0; i < 4; i++) {
            ar[i] = *(const bf16x8*)&Xr[mwo + 16*i + ml][kg * 8];
            union { bf16x8 v; u32 w[4]; } u;
            u.v = *(const bf16x8*)&Xi[mwo + 16*i + ml][kg * 8];
            ai[i] = u.v;
            u.w[0] ^= 0x80008000u; u.w[1] ^= 0x80008000u;
            u.w[2] ^= 0x80008000u; u.w[3] ^= 0x80008000u;
            nai[i] = u.v;
        }
        #pragma unroll
        for (int j = 0; j < 4; j++) {
            br[j] = *(const bf16x8*)&Wtr[nwo + 16*j + ml][kg * 8];
            bi[j] = *(const bf16x8*)&Wti[nwo + 16*j + ml][kg * 8];
        }
        // ---- MFMA: yr += ar*br - ai*bi ; yi += ar*bi + ai*br ----
        #pragma unroll
        for (int i = 0; i < 4; i++)
            #pragma unroll
            for (int j = 0; j < 4; j++) {
                accr[i][j] = MFMA16(ar[i],  br[j], accr[i][j], 0, 0, 0);
                accr[i][j] = MFMA16(nai[i], bi[j], accr[i][j], 0, 0, 0);
                acci[i][j] = MFMA16(ar[i],  bi[j], acci[i][j], 0, 0, 0);
                acci[i][j] = MFMA16(ai[i],  br[j], acci[i][j], 0, 0, 0);
            }
        __syncthreads();
    }

    // ---- epilogue: bias + fp32 store ----
    // C/D layout: col n = lane&15, row m = 4*(lane>>4) + reg  [m89-verified]
    #pragma unroll
    for (int j = 0; j < 4; j++) {
        const int n   = n0 + nwo + 16*j + ml;
        const float bre = job.br[n];
        const float bim = job.bi[n];
        #pragma unroll
        for (int i = 0; i < 4; i++) {
            #pragma unroll
            for (int r = 0; r < 4; r++) {
                const int m = m0 + mwo + 16*i + kg*4 + r;
                long addr;
                if (mode == 0) {
                    const int h = n >> 6, d = n & 63;
                    addr = ((long)h * SEQ + m) * HD + d;
                } else {
                    addr = (long)m * FDIM + n;
                }
                job.outR[addr] = accr[i][j][r] + bre;
                job.outI[addr] = acci[i][j][r] + bim;
            }
        }
    }
}

// Flash attention (fp32, online softmax). One block = (h, 32 q-rows), one batch.
// q-tile 32, k-tile 64. QKV [NH][SEQ][HD] fp32; A out [SEQ][FDIM] fp32.
__global__ __launch_bounds__(256)
void attn_flash(const float* __restrict__ Qr, const float* __restrict__ Qi,
                const float* __restrict__ Kr, const float* __restrict__ Ki,
                const float* __restrict__ Vr, const float* __restrict__ Vi,
                const float* __restrict__ mask,
                float* __restrict__ Ar, float* __restrict__ Ai)
{
    __shared__ float Qsr[32][68], Qsi[32][68];
    __shared__ float Ksr[64][68], Ksi[64][68];   // K tile, reused as V tile
    __shared__ float Pt[64][36];                 // P^T [k][q]
    __shared__ float mrow[32], lrow[32], arow[32];

    const int tid = threadIdx.x;
    const int q0  = blockIdx.x * 32;
    const int h   = blockIdx.y;
    const long base = (long)h * SEQ * HD;

    // ---- stage Q (once): thread -> (row tid>>3, 8 dims) ----
    {
        const int r = tid >> 3, d = (tid & 7) * 8;
        const float* s = Qr + base + (long)(q0 + r) * HD + d;
        *(float4*)&Qsr[r][d]     = *(const float4*)(s);
        *(float4*)&Qsr[r][d + 4] = *(const float4*)(s + 4);
        s = Qi + base + (long)(q0 + r) * HD + d;
        *(float4*)&Qsi[r][d]     = *(const float4*)(s);
        *(float4*)&Qsi[r][d + 4] = *(const float4*)(s + 4);
    }
    if (tid < 32) { mrow[tid] = -3.0e38f; lrow[tid] = 0.0f; }

    // roles
    const int sq = (tid >> 4) * 2;      // scores: 2 q-rows
    const int sk = (tid & 15) * 4;      // scores: 4 k-cols
    const int qg = tid >> 5;            // PV: 4 q-rows = 4*qg..
    const int dg = tid & 31;            // PV: d4 = 4*dg in [r(64)|i(64)]
    const int dd = (4 * dg) & 63;
    const int ri = dg >> 4;
    const int kvr = tid >> 2, kvd = (tid & 3) * 16;   // K/V staging
    const float scale = 0.125f;

    float4 oacc[4];
    #pragma unroll
    for (int i = 0; i < 4; i++) oacc[i] = make_float4(0.f, 0.f, 0.f, 0.f);

    for (int kt = 0; kt < SEQ; kt += 64) {
        __syncthreads();   // protect K/V LDS reuse (and Q staging, first iter)
        // ---- stage K ----
        {
            const float* s = Kr + base + (long)(kt + kvr) * HD + kvd;
            #pragma unroll
            for (int q = 0; q < 4; q++)
                *(float4*)&Ksr[kvr][kvd + 4*q] = *(const float4*)(s + 4*q);
            s = Ki + base + (long)(kt + kvr) * HD + kvd;
            #pragma unroll
            for (int q = 0; q < 4; q++)
                *(float4*)&Ksi[kvr][kvd + 4*q] = *(const float4*)(s + 4*q);
        }
        __syncthreads();

        // ---- scores: 2q x 4k per thread ----
        {
            float s00=0,s01=0,s02=0,s03=0, s10=0,s11=0,s12=0,s13=0;
            #pragma unroll
            for (int d = 0; d < 64; d += 4) {
                const float4 q0r = *(const float4*)&Qsr[sq][d];
                const float4 q1r = *(const float4*)&Qsr[sq+1][d];
                const float4 q0i = *(const float4*)&Qsi[sq][d];
                const float4 q1i = *(const float4*)&Qsi[sq+1][d];
                #pragma unroll
                for (int j = 0; j < 4; j++) {
                    const float4 kr = *(const float4*)&Ksr[sk+j][d];
                    const float4 ki = *(const float4*)&Ksi[sk+j][d];
                    const float a = q0r.x*kr.x + q0r.y*kr.y + q0r.z*kr.z + q0r.w*kr.w
                                  + q0i.x*ki.x + q0i.y*ki.y + q0i.z*ki.z + q0i.w*ki.w;
                    const float b = q1r.x*kr.x + q1r.y*kr.y + q1r.z*kr.z + q1r.w*kr.w
                                  + q1i.x*ki.x + q1i.y*ki.y + q1i.z*ki.z + q1i.w*ki.w;
                    if (j == 0) { s00 += a; s10 += b; }
                    else if (j == 1) { s01 += a; s11 += b; }
                    else if (j == 2) { s02 += a; s12 += b; }
                    else { s03 += a; s13 += b; }
                }
            }
            #pragma unroll
            for (int j = 0; j < 4; j++) {
                const float madd = (1.0f - mask[kt + sk + j]) * -1.0e9f;
                const float a = (j==0?s00:j==1?s01:j==2?s02:s03) * scale + madd;
                const float b = (j==0?s10:j==1?s11:j==2?s12:s13) * scale + madd;
                Pt[sk + j][sq]     = a;
                Pt[sk + j][sq + 1] = b;
            }
        }
        __syncthreads();

        // ---- stage V (overwrites K tile) + online softmax (owners tid<32) ----
        {
            const float* s = Vr + base + (long)(kt + kvr) * HD + kvd;
            #pragma unroll
            for (int q = 0; q < 4; q++)
                *(float4*)&Ksr[kvr][kvd + 4*q] = *(const float4*)(s + 4*q);
            s = Vi + base + (long)(kt + kvr) * HD + kvd;
            #pragma unroll
            for (int q = 0; q < 4; q++)
                *(float4*)&Ksi[kvr][kvd + 4*q] = *(const float4*)(s + 4*q);
        }
        if (tid < 32) {
            const int q = tid;
            float mx = -3.0e38f;
            #pragma unroll 8
            for (int k = 0; k < 64; k++) mx = fmaxf(mx, Pt[k][q]);
            const float mo = mrow[q];
            const float mn = fmaxf(mo, mx);
            const float al = __expf(mo - mn);
            float sum = 0.0f;
            #pragma unroll 8
            for (int k = 0; k < 64; k++) {
                const float p = __expf(Pt[k][q] - mn);
                Pt[k][q] = p;
                sum += p;
            }
            lrow[q] = lrow[q] * al + sum;
            arow[q] = al;
            mrow[q] = mn;
        }
        __syncthreads();

        // ---- rescale + PV: 4q x 4d per thread ----
        {
            #pragma unroll
            for (int i = 0; i < 4; i++) {
                const float al = arow[4*qg + i];
                oacc[i].x *= al; oacc[i].y *= al; oacc[i].z *= al; oacc[i].w *= al;
            }
            const float (*Vs)[68] = ri ? Ksi : Ksr;
            #pragma unroll 4
            for (int k = 0; k < 64; k++) {
                const float4 p = *(const float4*)&Pt[k][4*qg];
                const float4 v = *(const float4*)&Vs[k][dd];
                oacc[0].x += p.x*v.x; oacc[0].y += p.x*v.y; oacc[0].z += p.x*v.z; oacc[0].w += p.x*v.w;
                oacc[1].x += p.y*v.x; oacc[1].y += p.y*v.y; oacc[1].z += p.y*v.z; oacc[1].w += p.y*v.w;
                oacc[2].x += p.z*v.x; oacc[2].y += p.z*v.y; oacc[2].z += p.z*v.z; oacc[2].w += p.z*v.w;
                oacc[3].x += p.w*v.x; oacc[3].y += p.w*v.y; oacc[3].z += p.w*v.z; oacc[3].w += p.w*v.w;
            }
        }
    }

    // ---- epilogue: divide by l, store to A [2048][1024] ----
    float* outA = ri ? Ai : Ar;
    #pragma unroll
    for (int i = 0; i < 4; i++) {
        const float il = 1.0f / lrow[4*qg + i];
        float4 w;
        w.x = oacc[i].x * il; w.y = oacc[i].y * il;
        w.z = oacc[i].z * il; w.w = oacc[i].w * il;
        *(float4*)(outA + (long)(q0 + 4*qg + i) * FDIM + h * HD + dd) = w;
    }
}

extern "C" void kernel_launch(void* const* d_in, const int* in_sizes, int n_in,
                              void* d_out, int out_size, void* d_ws, size_t ws_size,
                              hipStream_t stream)
{
    const float* x_r  = (const float*)d_in[0];
    const float* x_i  = (const float*)d_in[1];
    const float* mask = (const float*)d_in[2];
    const float *Wq_r = (const float*)d_in[3],  *Wq_i = (const float*)d_in[4];
    const float *bq_r = (const float*)d_in[5],  *bq_i = (const float*)d_in[6];
    const float *Wk_r = (const float*)d_in[7],  *Wk_i = (const float*)d_in[8];
    const float *bk_r = (const float*)d_in[9],  *bk_i = (const float*)d_in[10];
    const float *Wv_r = (const float*)d_in[11], *Wv_i = (const float*)d_in[12];
    const float *bv_r = (const float*)d_in[13], *bv_i = (const float*)d_in[14];
    const float *Wo_r = (const float*)d_in[15], *Wo_i = (const float*)d_in[16];
    const float *bo_r = (const float*)d_in[17], *bo_i = (const float*)d_in[18];

    // Per-batch fp32 workspace: 8 x 2,097,152 floats = 64 MiB (validated footprint).
    float* ws = (float*)d_ws;
    const long NB = (long)SEQ * FDIM;
    float *Qr = ws + 0 * NB, *Qi = ws + 1 * NB;
    float *Kr = ws + 2 * NB, *Ki = ws + 3 * NB;
    float *Vr = ws + 4 * NB, *Vi = ws + 5 * NB;
    float *Ar = ws + 6 * NB, *Ai = ws + 7 * NB;

    const long HALF = (long)2 * SEQ * FDIM;

    for (int b = 0; b < 2; b++) {
        const float* xb_r = x_r + (long)b * NB;
        const float* xb_i = x_i + (long)b * NB;
        float* outR = (float*)d_out + (long)b * NB;
        float* outI = (float*)d_out + HALF + (long)b * NB;

        GemmJob jq = { Wq_r, Wq_i, bq_r, bq_i, Qr, Qi };
        GemmJob jk = { Wk_r, Wk_i, bk_r, bk_i, Kr, Ki };
        GemmJob jv = { Wv_r, Wv_i, bv_r, bv_i, Vr, Vi };
        cgemm_mfma<<<dim3(8, 16, 3), 256, 0, stream>>>(xb_r, xb_i, jq, jk, jv, 0);

        attn_flash<<<dim3(SEQ / 32, NH), 256, 0, stream>>>(Qr, Qi, Kr, Ki, Vr, Vi,
                                                           mask + (long)b * SEQ, Ar, Ai);

        GemmJob jo = { Wo_r, Wo_i, bo_r, bo_i, outR, outI };
        cgemm_mfma<<<dim3(8, 16, 1), 256, 0, stream>>>(Ar, Ai, jo, jo, jo, 1);
    }
}

// Round 9
// 618.145 us; speedup vs baseline: 13.6429x; 4.2672x over previous
//
#include <hip/hip_runtime.h>
#include <hip/hip_bf16.h>

typedef unsigned short u16;
typedef unsigned int   u32;
typedef __attribute__((ext_vector_type(8))) short bf16x8;
typedef __attribute__((ext_vector_type(4))) float f32x4;

#define FDIM 1024
#define NH   16
#define HD   64
#define SEQ  2048

#define MFMA16 __builtin_amdgcn_mfma_f32_16x16x32_bf16

__device__ __forceinline__ u16 f2bf(float f) {
    __hip_bfloat16 h = __float2bfloat16(f);
    return *reinterpret_cast<u16*>(&h);
}

// =====================================================================
// Projection GEMM (fp32 X, fp32 W -> bf16 out). 6 jobs via blockIdx.z:
// z = b*3 + t, t: 0=Q,1=K (out [h][s][d]) 2=V (out transposed [h][d][s]).
// Tile 128x128, BK=32, 4 waves x (64x64 quadrant as 4x4 MFMA tiles).
// =====================================================================
__global__ __launch_bounds__(256)
void proj_mfma(const float* __restrict__ xr_all, const float* __restrict__ xi_all,
               const float* __restrict__ Wqr, const float* __restrict__ Wqi,
               const float* __restrict__ bqr, const float* __restrict__ bqi,
               const float* __restrict__ Wkr, const float* __restrict__ Wki,
               const float* __restrict__ bkr, const float* __restrict__ bki,
               const float* __restrict__ Wvr, const float* __restrict__ Wvi,
               const float* __restrict__ bvr, const float* __restrict__ bvi,
               u16* __restrict__ ws)
{
    __shared__ u16 Xr[128][40], Xi[128][40];
    __shared__ u16 Wtr[128][40], Wti[128][40];    // transposed: [n][k]

    const int z = blockIdx.z, t = z % 3, b = z / 3;
    const float* xr = xr_all + (long)b * SEQ * FDIM;
    const float* xi = xi_all + (long)b * SEQ * FDIM;
    const float* wr = (t == 0) ? Wqr : (t == 1) ? Wkr : Wvr;
    const float* wi = (t == 0) ? Wqi : (t == 1) ? Wki : Wvi;
    const float* br = (t == 0) ? bqr : (t == 1) ? bkr : bvr;
    const float* bi = (t == 0) ? bqi : (t == 1) ? bki : bvi;
    const long TS = (long)2 * SEQ * FDIM;             // 4,194,304 per tensor
    u16* outR = ws + (long)(t * 2) * TS + (long)b * SEQ * FDIM;
    u16* outI = outR + TS;

    const int tid = threadIdx.x;
    const int n0  = blockIdx.x * 128;
    const int m0  = blockIdx.y * 128;

    const int lane = tid & 63;
    const int wv   = tid >> 6;
    const int mwo  = (wv >> 1) * 64;
    const int nwo  = (wv & 1) * 64;
    const int ml   = lane & 15;
    const int kg   = lane >> 4;

    const int sxm = tid >> 1;
    const int sxk = (tid & 1) * 16;
    const int swk = (tid >> 4) * 2;
    const int swn = tid & 15;

    f32x4 accr[4][4], acci[4][4];
    #pragma unroll
    for (int i = 0; i < 4; i++)
        #pragma unroll
        for (int j = 0; j < 4; j++) { accr[i][j] = (f32x4)(0.0f); acci[i][j] = (f32x4)(0.0f); }

    for (int k0 = 0; k0 < FDIM; k0 += 32) {
        {   // stage X -> bf16
            const float* s = xr + (long)(m0 + sxm) * FDIM + k0 + sxk;
            u16 tb[16];
            #pragma unroll
            for (int q = 0; q < 4; q++) {
                float4 v = *(const float4*)(s + q * 4);
                tb[q*4+0] = f2bf(v.x); tb[q*4+1] = f2bf(v.y);
                tb[q*4+2] = f2bf(v.z); tb[q*4+3] = f2bf(v.w);
            }
            *(uint4*)&Xr[sxm][sxk]     = *(uint4*)&tb[0];
            *(uint4*)&Xr[sxm][sxk + 8] = *(uint4*)&tb[8];
            s = xi + (long)(m0 + sxm) * FDIM + k0 + sxk;
            #pragma unroll
            for (int q = 0; q < 4; q++) {
                float4 v = *(const float4*)(s + q * 4);
                tb[q*4+0] = f2bf(v.x); tb[q*4+1] = f2bf(v.y);
                tb[q*4+2] = f2bf(v.z); tb[q*4+3] = f2bf(v.w);
            }
            *(uint4*)&Xi[sxm][sxk]     = *(uint4*)&tb[0];
            *(uint4*)&Xi[sxm][sxk + 8] = *(uint4*)&tb[8];
        }
        {   // stage W^T (k-pairs packed u32)
            const long rowA = (long)(k0 + swk) * FDIM + n0;
            const long rowB = rowA + FDIM;
            #pragma unroll
            for (int jj = 0; jj < 8; jj++) {
                const int n = swn + 16 * jj;
                float a = wr[rowA + n], c = wr[rowB + n];
                *(u32*)&Wtr[n][swk] = (u32)f2bf(a) | ((u32)f2bf(c) << 16);
                a = wi[rowA + n]; c = wi[rowB + n];
                *(u32*)&Wti[n][swk] = (u32)f2bf(a) | ((u32)f2bf(c) << 16);
            }
        }
        __syncthreads();

        bf16x8 ar[4], ai[4], nai[4], brf[4], bif[4];
        #pragma unroll
        for (int i = 0; i < 4; i++) {
            ar[i] = *(const bf16x8*)&Xr[mwo + 16*i + ml][kg * 8];
            union { bf16x8 v; u32 w[4]; } u;
            u.v = *(const bf16x8*)&Xi[mwo + 16*i + ml][kg * 8];
            ai[i] = u.v;
            u.w[0] ^= 0x80008000u; u.w[1] ^= 0x80008000u;
            u.w[2] ^= 0x80008000u; u.w[3] ^= 0x80008000u;
            nai[i] = u.v;
        }
        #pragma unroll
        for (int j = 0; j < 4; j++) {
            brf[j] = *(const bf16x8*)&Wtr[nwo + 16*j + ml][kg * 8];
            bif[j] = *(const bf16x8*)&Wti[nwo + 16*j + ml][kg * 8];
        }
        #pragma unroll
        for (int i = 0; i < 4; i++)
            #pragma unroll
            for (int j = 0; j < 4; j++) {
                accr[i][j] = MFMA16(ar[i],  brf[j], accr[i][j], 0, 0, 0);
                accr[i][j] = MFMA16(nai[i], bif[j], accr[i][j], 0, 0, 0);
                acci[i][j] = MFMA16(ar[i],  bif[j], acci[i][j], 0, 0, 0);
                acci[i][j] = MFMA16(ai[i],  brf[j], acci[i][j], 0, 0, 0);
            }
        __syncthreads();
    }

    // epilogue: bias + bf16 store. C/D: n = lane&15 (+16j+nwo), m = kg*4+reg (+16i+mwo).
    #pragma unroll
    for (int j = 0; j < 4; j++) {
        const int n = n0 + nwo + 16*j + ml;
        const int hh = n >> 6, d = n & 63;
        const float bre = br[n];
        const float bim = bi[n];
        #pragma unroll
        for (int i = 0; i < 4; i++) {
            const int mb = m0 + mwo + 16*i + kg*4;
            if (t < 2) {   // [h][s][d]
                #pragma unroll
                for (int r = 0; r < 4; r++) {
                    const long addr = ((long)hh * SEQ + (mb + r)) * HD + d;
                    outR[addr] = f2bf(accr[i][j][r] + bre);
                    outI[addr] = f2bf(acci[i][j][r] + bim);
                }
            } else {       // V transposed: [h][d][s], 4 consecutive m -> b64
                const long addr = ((long)hh * HD + d) * SEQ + mb;
                ushort4 vr, vi;
                vr.x = f2bf(accr[i][j][0] + bre); vr.y = f2bf(accr[i][j][1] + bre);
                vr.z = f2bf(accr[i][j][2] + bre); vr.w = f2bf(accr[i][j][3] + bre);
                vi.x = f2bf(acci[i][j][0] + bim); vi.y = f2bf(acci[i][j][1] + bim);
                vi.z = f2bf(acci[i][j][2] + bim); vi.w = f2bf(acci[i][j][3] + bim);
                *(ushort4*)&outR[addr] = vr;
                *(ushort4*)&outI[addr] = vi;
            }
        }
    }
}

// =====================================================================
// MFMA flash attention. Block = (128 q rows, head, batch); 4 waves x 32 q.
// S^T = K·Q^T via MFMA (A=K rows, B=Q rows, K-dim = 128 = re||im);
// softmax in registers (quad shfl reductions); P -> LDS bf16;
// O = P·V via MFMA (B = V^T rows, staged from pre-transposed global V).
// =====================================================================
__global__ __launch_bounds__(256)
void attn_mfma(const u16* __restrict__ Qr_g, const u16* __restrict__ Qi_g,
               const u16* __restrict__ Kr_g, const u16* __restrict__ Ki_g,
               const u16* __restrict__ Vtr_g, const u16* __restrict__ Vti_g,
               const float* __restrict__ mask_g,
               u16* __restrict__ Ar_g, u16* __restrict__ Ai_g)
{
    __shared__ u16 Kt[64][136];     // [key][dim 0..127 = re||im], stride 272 B (2-way ok)
    __shared__ u16 Vt[128][72];     // [dim][key], stride 144 B
    __shared__ u16 Pl[128][72];     // [q][key]
    __shared__ float madd[64];
    __shared__ float alphaW[128];
    __shared__ float linvW[128];

    const int tid  = threadIdx.x;
    const int lane = tid & 63;
    const int wv   = tid >> 6;
    const int ml   = lane & 15;
    const int quad = lane >> 4;
    const int q0   = blockIdx.x * 128;
    const int h    = blockIdx.y;
    const int b    = blockIdx.z;
    const long hb  = ((long)b * NH + h) * SEQ * HD;   // same size for [h][s][d] and [h][d][s]
    const float* mask = mask_g + (long)b * SEQ;

    // ---- Q fragments, held in registers for the whole kernel ----
    bf16x8 qf[2][4];
    #pragma unroll
    for (int nt = 0; nt < 2; nt++) {
        const long row = hb + (long)(q0 + wv*32 + nt*16 + ml) * HD;
        qf[nt][0] = *(const bf16x8*)(Qr_g + row + quad*8);
        qf[nt][1] = *(const bf16x8*)(Qr_g + row + 32 + quad*8);
        qf[nt][2] = *(const bf16x8*)(Qi_g + row + quad*8);
        qf[nt][3] = *(const bf16x8*)(Qi_g + row + 32 + quad*8);
    }

    f32x4 oacc[2][8];
    #pragma unroll
    for (int mt = 0; mt < 2; mt++)
        #pragma unroll
        for (int nt = 0; nt < 8; nt++) oacc[mt][nt] = (f32x4)(0.0f);
    float m_run[2] = {-3.0e38f, -3.0e38f};
    float l_run[2] = {0.0f, 0.0f};
    const float scale = 0.125f;

    for (int kt = 0; kt < SEQ; kt += 64) {
        __syncthreads();            // protect Kt/Vt reuse from previous iteration
        #pragma unroll
        for (int k = 0; k < 4; k++) {
            const int s = tid + 256 * k;
            {   // K tile: row = key, 16 dim-chunks of 8 (re 0..7, im 8..15)
                const int row = s >> 4, ch = s & 15;
                const u16* src = ((ch < 8) ? Kr_g : Ki_g) + hb + (long)(kt + row) * HD + (ch & 7) * 8;
                *(bf16x8*)&Kt[row][ch * 8] = *(const bf16x8*)src;
            }
            {   // V^T tile: row = dim (0..127 = re||im), 8 key-chunks of 8
                const int dim = s >> 3, kc = s & 7;
                const u16* src = ((dim < 64) ? Vtr_g : Vti_g) + hb + (long)(dim & 63) * SEQ + kt + kc * 8;
                *(bf16x8*)&Vt[dim][kc * 8] = *(const bf16x8*)src;
            }
        }
        if (tid < 64) madd[tid] = (1.0f - mask[kt + tid]) * -1.0e9f;
        __syncthreads();

        // ---- scores: S^T[key][q], 4 key-mtiles x 2 q-ntiles ----
        f32x4 sacc[4][2];
        #pragma unroll
        for (int mt = 0; mt < 4; mt++) { sacc[mt][0] = (f32x4)(0.0f); sacc[mt][1] = (f32x4)(0.0f); }
        #pragma unroll
        for (int mt = 0; mt < 4; mt++)
            #pragma unroll
            for (int kc = 0; kc < 4; kc++) {
                const bf16x8 kf = *(const bf16x8*)&Kt[mt*16 + ml][kc*32 + quad*8];
                sacc[mt][0] = MFMA16(kf, qf[0][kc], sacc[mt][0], 0, 0, 0);
                sacc[mt][1] = MFMA16(kf, qf[1][kc], sacc[mt][1], 0, 0, 0);
            }

        // ---- online softmax in registers; write P (bf16) ----
        #pragma unroll
        for (int nt = 0; nt < 2; nt++) {
            float sv[4][4];
            float mx = -3.0e38f;
            #pragma unroll
            for (int mt = 0; mt < 4; mt++) {
                const f32x4 md = *(const f32x4*)&madd[mt*16 + quad*4];
                #pragma unroll
                for (int r = 0; r < 4; r++) {
                    const float v = sacc[mt][nt][r] * scale + md[r];
                    sv[mt][r] = v;
                    mx = fmaxf(mx, v);
                }
            }
            mx = fmaxf(mx, __shfl_xor(mx, 16));
            mx = fmaxf(mx, __shfl_xor(mx, 32));
            const float mn = fmaxf(m_run[nt], mx);
            const float al = __expf(m_run[nt] - mn);
            float ps = 0.0f;
            const int qrow = wv*32 + nt*16 + ml;
            #pragma unroll
            for (int mt = 0; mt < 4; mt++) {
                const float p0 = __expf(sv[mt][0] - mn);
                const float p1 = __expf(sv[mt][1] - mn);
                const float p2 = __expf(sv[mt][2] - mn);
                const float p3 = __expf(sv[mt][3] - mn);
                ps += p0 + p1 + p2 + p3;
                ushort4 pb;
                pb.x = f2bf(p0); pb.y = f2bf(p1); pb.z = f2bf(p2); pb.w = f2bf(p3);
                *(ushort4*)&Pl[qrow][mt*16 + quad*4] = pb;
            }
            ps += __shfl_xor(ps, 16);
            ps += __shfl_xor(ps, 32);
            l_run[nt] = l_run[nt] * al + ps;
            m_run[nt] = mn;
            if (lane < 16) alphaW[wv*32 + nt*16 + lane] = al;
        }

        // ---- rescale O, then PV MFMA ----
        f32x4 al4[2];
        al4[0] = *(const f32x4*)&alphaW[wv*32 + quad*4];
        al4[1] = *(const f32x4*)&alphaW[wv*32 + 16 + quad*4];
        #pragma unroll
        for (int mt = 0; mt < 2; mt++)
            #pragma unroll
            for (int nt = 0; nt < 8; nt++) oacc[mt][nt] *= al4[mt];

        #pragma unroll
        for (int kc = 0; kc < 2; kc++) {
            const bf16x8 pf0 = *(const bf16x8*)&Pl[wv*32 + ml][kc*32 + quad*8];
            const bf16x8 pf1 = *(const bf16x8*)&Pl[wv*32 + 16 + ml][kc*32 + quad*8];
            #pragma unroll
            for (int nt = 0; nt < 8; nt++) {
                const bf16x8 vf = *(const bf16x8*)&Vt[nt*16 + ml][kc*32 + quad*8];
                oacc[0][nt] = MFMA16(pf0, vf, oacc[0][nt], 0, 0, 0);
                oacc[1][nt] = MFMA16(pf1, vf, oacc[1][nt], 0, 0, 0);
            }
        }
    }

    // ---- epilogue: divide by l, store A bf16 [s][1024] ----
    if (lane < 16) {
        linvW[wv*32 + lane]      = 1.0f / l_run[0];
        linvW[wv*32 + 16 + lane] = 1.0f / l_run[1];
    }
    f32x4 li[2];
    li[0] = *(const f32x4*)&linvW[wv*32 + quad*4];
    li[1] = *(const f32x4*)&linvW[wv*32 + 16 + quad*4];
    const long abase = (long)b * SEQ * FDIM;
    #pragma unroll
    for (int mt = 0; mt < 2; mt++)
        #pragma unroll
        for (int nt = 0; nt < 8; nt++) {
            const int dim = nt*16 + ml;
            u16* dst = ((dim < 64) ? Ar_g : Ai_g) + abase
                     + (long)(q0 + wv*32 + mt*16 + quad*4) * FDIM + h * HD + (dim & 63);
            #pragma unroll
            for (int r = 0; r < 4; r++)
                dst[(long)r * FDIM] = f2bf(oacc[mt][nt][r] * li[mt][r]);
        }
}

// =====================================================================
// O-projection GEMM (bf16 A in, fp32 W, fp32 out to d_out). z = batch.
// =====================================================================
__global__ __launch_bounds__(256)
void oproj_mfma(const u16* __restrict__ Ar_all, const u16* __restrict__ Ai_all,
                const float* __restrict__ Wor, const float* __restrict__ Woi,
                const float* __restrict__ bor, const float* __restrict__ boi,
                float* __restrict__ out)
{
    __shared__ u16 Xr[128][40], Xi[128][40];
    __shared__ u16 Wtr[128][40], Wti[128][40];

    const int b = blockIdx.z;
    const u16* ar = Ar_all + (long)b * SEQ * FDIM;
    const u16* ai = Ai_all + (long)b * SEQ * FDIM;
    float* outR = out + (long)b * SEQ * FDIM;
    float* outI = out + (long)2 * SEQ * FDIM + (long)b * SEQ * FDIM;

    const int tid = threadIdx.x;
    const int n0  = blockIdx.x * 128;
    const int m0  = blockIdx.y * 128;

    const int lane = tid & 63;
    const int wv   = tid >> 6;
    const int mwo  = (wv >> 1) * 64;
    const int nwo  = (wv & 1) * 64;
    const int ml   = lane & 15;
    const int kg   = lane >> 4;

    const int sxm = tid >> 1;
    const int sxk = (tid & 1) * 16;
    const int swk = (tid >> 4) * 2;
    const int swn = tid & 15;

    f32x4 accr[4][4], acci[4][4];
    #pragma unroll
    for (int i = 0; i < 4; i++)
        #pragma unroll
        for (int j = 0; j < 4; j++) { accr[i][j] = (f32x4)(0.0f); acci[i][j] = (f32x4)(0.0f); }

    for (int k0 = 0; k0 < FDIM; k0 += 32) {
        {   // stage X (already bf16): straight 16B copies
            const u16* s = ar + (long)(m0 + sxm) * FDIM + k0 + sxk;
            *(uint4*)&Xr[sxm][sxk]     = *(const uint4*)(s);
            *(uint4*)&Xr[sxm][sxk + 8] = *(const uint4*)(s + 8);
            s = ai + (long)(m0 + sxm) * FDIM + k0 + sxk;
            *(uint4*)&Xi[sxm][sxk]     = *(const uint4*)(s);
            *(uint4*)&Xi[sxm][sxk + 8] = *(const uint4*)(s + 8);
        }
        {   // stage W^T
            const long rowA = (long)(k0 + swk) * FDIM + n0;
            const long rowB = rowA + FDIM;
            #pragma unroll
            for (int jj = 0; jj < 8; jj++) {
                const int n = swn + 16 * jj;
                float a = Wor[rowA + n], c = Wor[rowB + n];
                *(u32*)&Wtr[n][swk] = (u32)f2bf(a) | ((u32)f2bf(c) << 16);
                a = Woi[rowA + n]; c = Woi[rowB + n];
                *(u32*)&Wti[n][swk] = (u32)f2bf(a) | ((u32)f2bf(c) << 16);
            }
        }
        __syncthreads();

        bf16x8 arf[4], aif[4], naif[4], brf[4], bif[4];
        #pragma unroll
        for (int i = 0; i < 4; i++) {
            arf[i] = *(const bf16x8*)&Xr[mwo + 16*i + ml][kg * 8];
            union { bf16x8 v; u32 w[4]; } u;
            u.v = *(const bf16x8*)&Xi[mwo + 16*i + ml][kg * 8];
            aif[i] = u.v;
            u.w[0] ^= 0x80008000u; u.w[1] ^= 0x80008000u;
            u.w[2] ^= 0x80008000u; u.w[3] ^= 0x80008000u;
            naif[i] = u.v;
        }
        #pragma unroll
        for (int j = 0; j < 4; j++) {
            brf[j] = *(const bf16x8*)&Wtr[nwo + 16*j + ml][kg * 8];
            bif[j] = *(const bf16x8*)&Wti[nwo + 16*j + ml][kg * 8];
        }
        #pragma unroll
        for (int i = 0; i < 4; i++)
            #pragma unroll
            for (int j = 0; j < 4; j++) {
                accr[i][j] = MFMA16(arf[i],  brf[j], accr[i][j], 0, 0, 0);
                accr[i][j] = MFMA16(naif[i], bif[j], accr[i][j], 0, 0, 0);
                acci[i][j] = MFMA16(arf[i],  bif[j], acci[i][j], 0, 0, 0);
                acci[i][j] = MFMA16(aif[i],  brf[j], acci[i][j], 0, 0, 0);
            }
        __syncthreads();
    }

    #pragma unroll
    for (int j = 0; j < 4; j++) {
        const int n = n0 + nwo + 16*j + ml;
        const float bre = bor[n];
        const float bim = boi[n];
        #pragma unroll
        for (int i = 0; i < 4; i++) {
            #pragma unroll
            for (int r = 0; r < 4; r++) {
                const int m = m0 + mwo + 16*i + kg*4 + r;
                const long addr = (long)m * FDIM + n;
                outR[addr] = accr[i][j][r] + bre;
                outI[addr] = acci[i][j][r] + bim;
            }
        }
    }
}

extern "C" void kernel_launch(void* const* d_in, const int* in_sizes, int n_in,
                              void* d_out, int out_size, void* d_ws, size_t ws_size,
                              hipStream_t stream)
{
    const float* x_r  = (const float*)d_in[0];
    const float* x_i  = (const float*)d_in[1];
    const float* mask = (const float*)d_in[2];
    const float *Wq_r = (const float*)d_in[3],  *Wq_i = (const float*)d_in[4];
    const float *bq_r = (const float*)d_in[5],  *bq_i = (const float*)d_in[6];
    const float *Wk_r = (const float*)d_in[7],  *Wk_i = (const float*)d_in[8];
    const float *bk_r = (const float*)d_in[9],  *bk_i = (const float*)d_in[10];
    const float *Wv_r = (const float*)d_in[11], *Wv_i = (const float*)d_in[12];
    const float *bv_r = (const float*)d_in[13], *bv_i = (const float*)d_in[14];
    const float *Wo_r = (const float*)d_in[15], *Wo_i = (const float*)d_in[16];
    const float *bo_r = (const float*)d_in[17], *bo_i = (const float*)d_in[18];

    // bf16 workspace, both batches: 8 tensors x 4,194,304 u16 = 64 MiB.
    // Order: Qr Qi Kr Ki Vtr Vti Ar Ai. Q/K: [b][h][s][d]; Vt: [b][h][d][s]; A: [b][s][1024].
    u16* ws = (u16*)d_ws;
    const long TS = (long)2 * SEQ * FDIM;
    u16 *Qr = ws,          *Qi = ws + TS;
    u16 *Kr = ws + 2*TS,   *Ki = ws + 3*TS;
    u16 *Vtr = ws + 4*TS,  *Vti = ws + 5*TS;
    u16 *Ar = ws + 6*TS,   *Ai = ws + 7*TS;

    proj_mfma<<<dim3(8, 16, 6), 256, 0, stream>>>(x_r, x_i,
        Wq_r, Wq_i, bq_r, bq_i, Wk_r, Wk_i, bk_r, bk_i, Wv_r, Wv_i, bv_r, bv_i, ws);

    attn_mfma<<<dim3(SEQ / 128, NH, 2), 256, 0, stream>>>(Qr, Qi, Kr, Ki, Vtr, Vti,
                                                          mask, Ar, Ai);

    oproj_mfma<<<dim3(8, 16, 2), 256, 0, stream>>>(Ar, Ai, Wo_r, Wo_i, bo_r, bo_i,
                                                   (float*)d_out);
}